// Round 8
// baseline (413.682 us; speedup 1.0000x reference)
//
#include <hip/hip_runtime.h>

typedef __bf16 bf16;
typedef __bf16 bf16x4 __attribute__((ext_vector_type(4)));
typedef __bf16 bf16x8 __attribute__((ext_vector_type(8)));
typedef float f32x4 __attribute__((ext_vector_type(4)));

__device__ __forceinline__ f32x4 MFMA16(bf16x8 a, bf16x8 b, f32x4 c) {
  return __builtin_amdgcn_mfma_f32_16x16x32_bf16(a, b, c, 0, 0, 0);
}

__device__ __forceinline__ bf16 split_hi(float v) { return (bf16)v; }
__device__ __forceinline__ bf16 split_lo(float v) { return (bf16)(v - (float)(bf16)v); }

// ---- f32 -> bf16 bulk convert ----
__global__ void k_cvt(const float* __restrict__ in, bf16* __restrict__ out, long n) {
  const long i = ((long)blockIdx.x * 256 + threadIdx.x) * 4;
  if (i < n) {
    const f32x4 v = *(const f32x4*)&in[i];
    bf16x4 o;
#pragma unroll
    for (int j = 0; j < 4; ++j) o[j] = (bf16)v[j];
    *(bf16x4*)&out[i] = o;
  }
}

// ---- Wc[b][d][r] = sum_k w[b,k] * neurons[idx[b,k]][d][r]  (f32 out) ----
__global__ void k_build_wc(const float* __restrict__ neurons, const float* __restrict__ w,
                           const int* __restrict__ idx, float* __restrict__ Wc) {
  const int d = blockIdx.x, b = blockIdx.y, r = threadIdx.x;
  float acc = 0.f;
#pragma unroll
  for (int k = 0; k < 16; ++k) {
    const float wk = w[b * 16 + k];
    const int ni = idx[b * 16 + k];
    acc += wk * neurons[((long)ni * 1024 + d) * 128 + r];
  }
  Wc[((long)b * 1024 + d) * 128 + r] = acc;
}

// ---- Wn[z=which*8+b][r][d] = sum_k w[b,k] * pool[idx[b,k]][r][d]  (f32 out) ----
__global__ void k_build_mix(const float* __restrict__ pool,
                            const float* __restrict__ wq, const int* __restrict__ iq,
                            const float* __restrict__ wk, const int* __restrict__ ik,
                            const float* __restrict__ wv, const int* __restrict__ iv,
                            float* __restrict__ Wn) {
  const int d = blockIdx.x * 256 + threadIdx.x;
  const int r = blockIdx.y;
  const int z = blockIdx.z, which = z >> 3, b = z & 7;
  const float* wp = which == 0 ? wq : (which == 1 ? wk : wv);
  const int* ip = which == 0 ? iq : (which == 1 ? ik : iv);
  float acc = 0.f;
#pragma unroll
  for (int k = 0; k < 8; ++k) {
    const float wkk = wp[b * 8 + k];
    const int ni = ip[b * 8 + k];
    acc += wkk * pool[((long)ni * 128 + r) * 1024 + d];
  }
  Wn[((long)z * 128 + r) * 1024 + d] = acc;
}

// ---- batched transpose [M][N] -> [N][M] (z = batch) ----
template <typename T>
__global__ void k_transpose(const T* __restrict__ in, T* __restrict__ out, int M, int N) {
  __shared__ T t[64][65];
  const int n0 = blockIdx.x * 64, m0 = blockIdx.y * 64;
  const long base = (long)blockIdx.z * M * N;
  const int tid = threadIdx.x;
#pragma unroll
  for (int i = 0; i < 16; ++i) {
    const int lin = i * 256 + tid;
    const int r = lin >> 6, c = lin & 63;
    t[r][c] = in[base + (long)(m0 + r) * N + (n0 + c)];
  }
  __syncthreads();
#pragma unroll
  for (int i = 0; i < 16; ++i) {
    const int lin = i * 256 + tid;
    const int r = lin >> 6, c = lin & 63;
    out[base + (long)(n0 + r) * M + (m0 + c)] = t[c][r];
  }
}

// ---- split-precision GEMM: C = A(MxK,f32) * Bt[n][k](f32), scaled.
// mode: 0 = bf16 out, 1 = f32 out, 2 = split-pair bf16 out (C=hi, C2=lo).
// split_heads: C[(col/64)][row][col%64] per 64-col head. 4 waves 2x2 of 
// (BM/2)x(BN/2) each.
template <int BM, int BN>
__global__ __launch_bounds__(256) void k_gemm_split(
    const float* __restrict__ A, const float* __restrict__ Bt, void* __restrict__ C,
    bf16* __restrict__ C2, int M, int N, int K, long sA, long sB, long sC,
    int split_heads, int mode, float scale) {
  constexpr int BK = 32, LDR = 40;
  constexpr int MT = BM / 32, NT = BN / 32;
  __shared__ __align__(16) bf16 Ash[BM * LDR], Asl[BM * LDR];
  __shared__ __align__(16) bf16 Bsh[BN * LDR], Bsl[BN * LDR];
  const int tid = threadIdx.x, wave = tid >> 6, lane = tid & 63;
  const int quad = lane >> 4, l16 = lane & 15;
  const int wrow = wave >> 1, wcol = wave & 1;
  const int z = blockIdx.z;
  const float* Ap = A + (long)z * sA;
  const float* Bp = Bt + (long)z * sB;
  const long m0 = (long)blockIdx.y * BM, n0 = (long)blockIdx.x * BN;
  f32x4 acc[MT][NT];
#pragma unroll
  for (int mt = 0; mt < MT; ++mt)
#pragma unroll
    for (int nt = 0; nt < NT; ++nt) acc[mt][nt] = (f32x4){0.f, 0.f, 0.f, 0.f};
  for (int k0 = 0; k0 < K; k0 += BK) {
#pragma unroll
    for (int i = 0; i < BM / 32; ++i) {
      const int c = i * 256 + tid, r = c >> 3, c4 = c & 7;
      const f32x4 v = *(const f32x4*)&Ap[(m0 + r) * K + k0 + c4 * 4];
      bf16x4 h4, l4;
#pragma unroll
      for (int j = 0; j < 4; ++j) { h4[j] = split_hi(v[j]); l4[j] = split_lo(v[j]); }
      *(bf16x4*)&Ash[r * LDR + c4 * 4] = h4;
      *(bf16x4*)&Asl[r * LDR + c4 * 4] = l4;
    }
#pragma unroll
    for (int i = 0; i < BN / 32; ++i) {
      const int c = i * 256 + tid, r = c >> 3, c4 = c & 7;
      const f32x4 v = *(const f32x4*)&Bp[(n0 + r) * K + k0 + c4 * 4];
      bf16x4 h4, l4;
#pragma unroll
      for (int j = 0; j < 4; ++j) { h4[j] = split_hi(v[j]); l4[j] = split_lo(v[j]); }
      *(bf16x4*)&Bsh[r * LDR + c4 * 4] = h4;
      *(bf16x4*)&Bsl[r * LDR + c4 * 4] = l4;
    }
    __syncthreads();
    bf16x8 ah[MT], al[MT], bh[NT], bl[NT];
#pragma unroll
    for (int mt = 0; mt < MT; ++mt) {
      const int row = wrow * (MT * 16) + mt * 16 + l16;
      ah[mt] = *(const bf16x8*)&Ash[row * LDR + quad * 8];
      al[mt] = *(const bf16x8*)&Asl[row * LDR + quad * 8];
    }
#pragma unroll
    for (int nt = 0; nt < NT; ++nt) {
      const int row = wcol * (NT * 16) + nt * 16 + l16;
      bh[nt] = *(const bf16x8*)&Bsh[row * LDR + quad * 8];
      bl[nt] = *(const bf16x8*)&Bsl[row * LDR + quad * 8];
    }
#pragma unroll
    for (int mt = 0; mt < MT; ++mt)
#pragma unroll
      for (int nt = 0; nt < NT; ++nt) {
        acc[mt][nt] = MFMA16(ah[mt], bh[nt], acc[mt][nt]);
        acc[mt][nt] = MFMA16(ah[mt], bl[nt], acc[mt][nt]);
        acc[mt][nt] = MFMA16(al[mt], bh[nt], acc[mt][nt]);
      }
    __syncthreads();
  }
  bf16* Cb = (bf16*)C + (long)z * sC;
  float* Cf = (float*)C + (long)z * sC;
  bf16* C2b = C2 + (long)z * sC;
#pragma unroll
  for (int mt = 0; mt < MT; ++mt)
#pragma unroll
    for (int nt = 0; nt < NT; ++nt)
#pragma unroll
      for (int r = 0; r < 4; ++r) {
        const long row = m0 + wrow * (MT * 16) + mt * 16 + quad * 4 + r;
        const long col = n0 + wcol * (NT * 16) + nt * 16 + l16;
        const float v = acc[mt][nt][r] * scale;
        const long off = split_heads
                             ? ((col >> 6) * ((long)M * 64) + row * 64 + (col & 63))
                             : (row * (long)N + col);
        if (mode == 1) {
          Cf[off] = v;
        } else if (mode == 0) {
          Cb[off] = (bf16)v;
        } else {
          const bf16 hi = (bf16)v;
          Cb[off] = hi;
          C2b[off] = (bf16)(v - (float)hi);
        }
      }
}

// ---- plain bf16 GEMM (output projection): C = A(MxK) * Bt[n][k], out f32. ----
template <int BM, int BN>
__global__ __launch_bounds__(256) void k_gemm_bt(
    const bf16* __restrict__ A, const bf16* __restrict__ Bt, float* __restrict__ C,
    int M, int N, int K) {
  constexpr int BK = 32, LDR = BK + 8;
  constexpr int MT = BM / 32, NT = BN / 32;
  __shared__ __align__(16) bf16 As[BM * LDR];
  __shared__ __align__(16) bf16 Bs[BN * LDR];
  const int tid = threadIdx.x, wave = tid >> 6, lane = tid & 63;
  const int quad = lane >> 4, l16 = lane & 15;
  const int wrow = wave >> 1, wcol = wave & 1;
  const long m0 = (long)blockIdx.y * BM, n0 = (long)blockIdx.x * BN;
  f32x4 acc[MT][NT];
#pragma unroll
  for (int mt = 0; mt < MT; ++mt)
#pragma unroll
    for (int nt = 0; nt < NT; ++nt) acc[mt][nt] = (f32x4){0.f, 0.f, 0.f, 0.f};
  constexpr int ACH = BM * BK / 8 / 256;
  constexpr int BCH = BN * BK / 8 / 256;
  for (int k0 = 0; k0 < K; k0 += BK) {
#pragma unroll
    for (int i = 0; i < ACH; ++i) {
      const int c = i * 256 + tid, r = c >> 2, c4 = c & 3;
      *(bf16x8*)&As[r * LDR + c4 * 8] = *(const bf16x8*)&A[(m0 + r) * K + k0 + c4 * 8];
    }
#pragma unroll
    for (int i = 0; i < BCH; ++i) {
      const int c = i * 256 + tid, r = c >> 2, c4 = c & 3;
      *(bf16x8*)&Bs[r * LDR + c4 * 8] = *(const bf16x8*)&Bt[(n0 + r) * K + k0 + c4 * 8];
    }
    __syncthreads();
    bf16x8 af[MT], bfr[NT];
#pragma unroll
    for (int mt = 0; mt < MT; ++mt)
      af[mt] = *(const bf16x8*)&As[(wrow * MT * 16 + mt * 16 + l16) * LDR + quad * 8];
#pragma unroll
    for (int nt = 0; nt < NT; ++nt)
      bfr[nt] = *(const bf16x8*)&Bs[(wcol * NT * 16 + nt * 16 + l16) * LDR + quad * 8];
#pragma unroll
    for (int mt = 0; mt < MT; ++mt)
#pragma unroll
      for (int nt = 0; nt < NT; ++nt)
        acc[mt][nt] = MFMA16(af[mt], bfr[nt], acc[mt][nt]);
    __syncthreads();
  }
#pragma unroll
  for (int mt = 0; mt < MT; ++mt)
#pragma unroll
    for (int nt = 0; nt < NT; ++nt)
#pragma unroll
      for (int r = 0; r < 4; ++r) {
        const long row = m0 + wrow * MT * 16 + mt * 16 + quad * 4 + r;
        const long col = n0 + wcol * NT * 16 + nt * 16 + l16;
        C[row * (long)N + col] = acc[mt][nt][r];
      }
}

// ---- causal flash attention, paired q-tiles for uniform load + shared staging.
// Qhi/Qlo/Khi/Klo: [B*H][S][64] bf16 (Q pre-scaled by 1/8). Vt: [B][16][64][S].
// Out att: [B][S][1024] bf16. Block p handles q-tiles p and 7-p (128 rows each).
// Grid (4, B*H). 4 waves x 32 q-rows per tile.
__global__ __launch_bounds__(256) void k_attn(
    const bf16* __restrict__ Qhi, const bf16* __restrict__ Qlo,
    const bf16* __restrict__ Khi, const bf16* __restrict__ Klo,
    const bf16* __restrict__ Vtg, bf16* __restrict__ Og) {
  __shared__ __align__(16) bf16 KhiS[64 * 72], KloS[64 * 72];  // [key][dh]
  __shared__ __align__(16) bf16 VtS[64 * 72];                  // [dh][key]
  __shared__ __align__(16) bf16 Ps[4 * 32 * 72];               // per-wave P
  const int p = blockIdx.x, bh = blockIdx.y;
  const int b = bh >> 4, hh = bh & 15;
  const int tid = threadIdx.x, wave = tid >> 6, lane = tid & 63;
  const int quad = lane >> 4, l16 = lane & 15;
  const long bhS = (long)bh * 1024 * 64;
  const bf16* KhiG = Khi + bhS;
  const bf16* KloG = Klo + bhS;
  const bf16* VtG = Vtg + (long)bh * 64 * 1024;
  const int qbwA = p * 128 + wave * 32;        // light tile
  const int qbwB = (7 - p) * 128 + wave * 32;  // heavy tile
  bf16x8 qhA[2][2], qlA[2][2], qhB[2][2], qlB[2][2];
#pragma unroll
  for (int m = 0; m < 2; ++m) {
    const long rA = (long)(qbwA + m * 16 + l16) * 64;
    const long rB = (long)(qbwB + m * 16 + l16) * 64;
#pragma unroll
    for (int s = 0; s < 2; ++s) {
      qhA[m][s] = *(const bf16x8*)&Qhi[bhS + rA + s * 32 + quad * 8];
      qlA[m][s] = *(const bf16x8*)&Qlo[bhS + rA + s * 32 + quad * 8];
      qhB[m][s] = *(const bf16x8*)&Qhi[bhS + rB + s * 32 + quad * 8];
      qlB[m][s] = *(const bf16x8*)&Qlo[bhS + rB + s * 32 + quad * 8];
    }
  }
  const f32x4 zero4 = {0.f, 0.f, 0.f, 0.f};
  f32x4 oA[2][4], oB[2][4];
  float mA[2][4], lA[2][4], mB[2][4], lB[2][4];
#pragma unroll
  for (int m = 0; m < 2; ++m)
#pragma unroll
    for (int r = 0; r < 4; ++r) {
      mA[m][r] = -1.0e30f; lA[m][r] = 0.f;
      mB[m][r] = -1.0e30f; lB[m][r] = 0.f;
    }
#pragma unroll
  for (int m = 0; m < 2; ++m)
#pragma unroll
    for (int nt = 0; nt < 4; ++nt) { oA[m][nt] = zero4; oB[m][nt] = zero4; }

  auto tile_compute = [&](const bf16x8 (&qh)[2][2], const bf16x8 (&ql)[2][2],
                          f32x4 (&o)[2][4], float (&m_i)[2][4], float (&l_i)[2][4],
                          int qbw, int kb) {
    f32x4 sc[2][4];
#pragma unroll
    for (int ct = 0; ct < 4; ++ct) {
      const int krow = ct * 16 + l16;
      const bf16x8 kh0 = *(const bf16x8*)&KhiS[krow * 72 + quad * 8];
      const bf16x8 kh1 = *(const bf16x8*)&KhiS[krow * 72 + 32 + quad * 8];
      const bf16x8 kl0 = *(const bf16x8*)&KloS[krow * 72 + quad * 8];
      const bf16x8 kl1 = *(const bf16x8*)&KloS[krow * 72 + 32 + quad * 8];
#pragma unroll
      for (int m = 0; m < 2; ++m) {
        f32x4 s = MFMA16(qh[m][0], kh0, zero4);
        s = MFMA16(qh[m][1], kh1, s);
        s = MFMA16(qh[m][0], kl0, s);
        s = MFMA16(qh[m][1], kl1, s);
        s = MFMA16(ql[m][0], kh0, s);
        s = MFMA16(ql[m][1], kh1, s);
        sc[m][ct] = s;
      }
    }
    if (kb + 63 > qbw) {  // diagonal region: causal mask
#pragma unroll
      for (int ct = 0; ct < 4; ++ct) {
        const int col = kb + ct * 16 + l16;
#pragma unroll
        for (int m = 0; m < 2; ++m)
#pragma unroll
          for (int r = 0; r < 4; ++r) {
            const int row = qbw + m * 16 + quad * 4 + r;
            if (col > row) sc[m][ct][r] = -1.0e30f;
          }
      }
    }
#pragma unroll
    for (int m = 0; m < 2; ++m) {
      float rmax[4], alpha[4], rsum[4];
#pragma unroll
      for (int r = 0; r < 4; ++r)
        rmax[r] = fmaxf(fmaxf(sc[m][0][r], sc[m][1][r]), fmaxf(sc[m][2][r], sc[m][3][r]));
#pragma unroll
      for (int off = 1; off < 16; off <<= 1)
#pragma unroll
        for (int r = 0; r < 4; ++r) rmax[r] = fmaxf(rmax[r], __shfl_xor(rmax[r], off));
#pragma unroll
      for (int r = 0; r < 4; ++r) {
        const float mnew = fmaxf(m_i[m][r], rmax[r]);
        alpha[r] = __expf(m_i[m][r] - mnew);
        m_i[m][r] = mnew;
        rsum[r] = 0.f;
      }
#pragma unroll
      for (int ct = 0; ct < 4; ++ct)
#pragma unroll
        for (int r = 0; r < 4; ++r) {
          const float pr = __expf(sc[m][ct][r] - m_i[m][r]);
          sc[m][ct][r] = pr;
          rsum[r] += pr;
        }
#pragma unroll
      for (int off = 1; off < 16; off <<= 1)
#pragma unroll
        for (int r = 0; r < 4; ++r) rsum[r] += __shfl_xor(rsum[r], off);
#pragma unroll
      for (int r = 0; r < 4; ++r) l_i[m][r] = l_i[m][r] * alpha[r] + rsum[r];
#pragma unroll
      for (int nt = 0; nt < 4; ++nt)
#pragma unroll
        for (int r = 0; r < 4; ++r) o[m][nt][r] *= alpha[r];
#pragma unroll
      for (int ct = 0; ct < 4; ++ct)
#pragma unroll
        for (int r = 0; r < 4; ++r)
          Ps[wave * 2304 + (m * 16 + quad * 4 + r) * 72 + ct * 16 + l16] =
              (bf16)sc[m][ct][r];
    }
    bf16x8 ap[2][2];
#pragma unroll
    for (int m = 0; m < 2; ++m) {
      ap[m][0] = *(const bf16x8*)&Ps[wave * 2304 + (m * 16 + l16) * 72 + quad * 8];
      ap[m][1] = *(const bf16x8*)&Ps[wave * 2304 + (m * 16 + l16) * 72 + 32 + quad * 8];
    }
#pragma unroll
    for (int nt = 0; nt < 4; ++nt) {
      const bf16x8 bv0 = *(const bf16x8*)&VtS[(nt * 16 + l16) * 72 + quad * 8];
      const bf16x8 bv1 = *(const bf16x8*)&VtS[(nt * 16 + l16) * 72 + 32 + quad * 8];
#pragma unroll
      for (int m = 0; m < 2; ++m) {
        o[m][nt] = MFMA16(ap[m][0], bv0, o[m][nt]);
        o[m][nt] = MFMA16(ap[m][1], bv1, o[m][nt]);
      }
    }
  };

  const int nch = 2 * (7 - p) + 2;  // chunks needed by the heavy tile
  for (int kc = 0; kc < nch; ++kc) {
    const int kb = kc * 64;
#pragma unroll
    for (int i = 0; i < 2; ++i) {
      const int c = i * 256 + tid, r = c >> 3, c8 = c & 7;
      *(bf16x8*)&KhiS[r * 72 + c8 * 8] = *(const bf16x8*)&KhiG[(long)(kb + r) * 64 + c8 * 8];
      *(bf16x8*)&KloS[r * 72 + c8 * 8] = *(const bf16x8*)&KloG[(long)(kb + r) * 64 + c8 * 8];
      *(bf16x8*)&VtS[r * 72 + c8 * 8] = *(const bf16x8*)&VtG[(long)r * 1024 + kb + c8 * 8];
    }
    __syncthreads();
    if (kb <= qbwA + 31) tile_compute(qhA, qlA, oA, mA, lA, qbwA, kb);
    if (kb <= qbwB + 31) tile_compute(qhB, qlB, oB, mB, lB, qbwB, kb);
    __syncthreads();
  }
#pragma unroll
  for (int t = 0; t < 2; ++t) {
    const int qbw = t ? qbwB : qbwA;
#pragma unroll
    for (int m = 0; m < 2; ++m) {
      float inv[4];
#pragma unroll
      for (int r = 0; r < 4; ++r) inv[r] = 1.f / (t ? lB[m][r] : lA[m][r]);
#pragma unroll
      for (int nt = 0; nt < 4; ++nt)
#pragma unroll
        for (int r = 0; r < 4; ++r) {
          const int row = qbw + m * 16 + quad * 4 + r;
          const float v = (t ? oB[m][nt][r] : oA[m][nt][r]) * inv[r];
          Og[((long)b * 1024 + row) * 1024 + hh * 64 + nt * 16 + l16] = (bf16)v;
        }
    }
  }
}

extern "C" void kernel_launch(void* const* d_in, const int* in_sizes, int n_in,
                              void* d_out, int out_size, void* d_ws, size_t ws_size,
                              hipStream_t stream) {
  const float* x = (const float*)d_in[0];
  const float* cw = (const float*)d_in[1];
  const int* cidx = (const int*)d_in[2];
  const float* wq = (const float*)d_in[3];
  const int* iq = (const int*)d_in[4];
  const float* wk = (const float*)d_in[5];
  const int* ik = (const int*)d_in[6];
  const float* wv = (const float*)d_in[7];
  const int* iv = (const int*)d_in[8];
  const float* neurons = (const float*)d_in[9];
  const float* pool = (const float*)d_in[10];
  const float* WO = (const float*)d_in[11];
  float* out = (float*)d_out;
  char* ws = (char*)d_ws;
  // Workspace (86 MB peak, lifetime-overlapped):
  //   [ 0,16) Khi bf16 | [16,32) Klo bf16 | [32,48) Vt bf16 [8][16][64][1024]
  //   [48,64) att bf16  -- prep overlay: Wc f32 [48,52), Wn f32 [52,64)
  //   [64,68) WcT f32 | [68,80) Wt f32 [24][1024][128] | [80,84) h f32 | [84,86) WOb
  //   Qhi/Qlo bf16 in d_out (2 x 16 MB), dead before the final f32 write.
  bf16* Khi = (bf16*)(ws + (0l << 20));
  bf16* Klo = (bf16*)(ws + (16l << 20));
  bf16* Vt = (bf16*)(ws + (32l << 20));
  bf16* att = (bf16*)(ws + (48l << 20));
  float* Wc = (float*)(ws + (48l << 20));
  float* Wn = (float*)(ws + (52l << 20));
  float* WcT = (float*)(ws + (64l << 20));
  float* Wt = (float*)(ws + (68l << 20));
  float* h = (float*)(ws + (80l << 20));
  bf16* WOb = (bf16*)(ws + (84l << 20));
  bf16* Qhi = (bf16*)d_out;
  bf16* Qlo = (bf16*)d_out + (8l << 20);

  k_cvt<<<1024, 256, 0, stream>>>(WO, WOb, 1024l * 1024);
  k_build_wc<<<dim3(1024, 8), 128, 0, stream>>>(neurons, cw, cidx, Wc);
  k_build_mix<<<dim3(4, 128, 24), 256, 0, stream>>>(pool, wq, iq, wk, ik, wv, iv, Wn);
  k_transpose<float><<<dim3(2, 16, 8), 256, 0, stream>>>(Wc, WcT, 1024, 128);
  k_transpose<float><<<dim3(16, 2, 24), 256, 0, stream>>>(Wn, Wt, 128, 1024);
  // h[b] = x[b] (1024x1024) * Wc[b] (1024x128), split-precision, f32 out
  k_gemm_split<64, 64><<<dim3(2, 16, 8), 256, 0, stream>>>(
      x, WcT, h, nullptr, 1024, 128, 1024, 1l << 20, 1l << 17, 1l << 17, 0, 1, 1.f);
  // Q = (h*Wq)/8 pre-split into Qhi/Qlo (head-split layout)
  k_gemm_split<128, 128><<<dim3(8, 8, 8), 256, 0, stream>>>(
      h, Wt, Qhi, Qlo, 1024, 1024, 128, 1l << 17, 1l << 17, 1l << 20, 1, 2, 0.125f);
  // K pre-split into Khi/Klo (head-split layout)
  k_gemm_split<128, 128><<<dim3(8, 8, 8), 256, 0, stream>>>(
      h, Wt + (8l << 17), Khi, Klo, 1024, 1024, 128, 1l << 17, 1l << 17, 1l << 20, 1, 2, 1.f);
  // V^T directly: Vt[z] = Wt_V[z] (1024d x 128r) * h[z]^T -> [d][s]
  k_gemm_split<128, 128><<<dim3(8, 8, 8), 256, 0, stream>>>(
      Wt + (16l << 17), h, Vt, nullptr, 1024, 1024, 128, 1l << 17, 1l << 17, 1l << 20, 0, 0, 1.f);
  k_attn<<<dim3(4, 128), 256, 0, stream>>>(Qhi, Qlo, Khi, Klo, Vt, att);
  // out(f32, 8192x1024) = att * W_O^T (W_O [d_out][d_in] is already Bt layout)
  k_gemm_bt<128, 128><<<dim3(8, 64, 1), 256, 0, stream>>>(att, WOb, out, 8192, 1024, 1024);
}

// Round 9
// 389.342 us; speedup vs baseline: 1.0625x; 1.0625x over previous
//
#include <hip/hip_runtime.h>

typedef __bf16 bf16;
typedef __bf16 bf16x4 __attribute__((ext_vector_type(4)));
typedef __bf16 bf16x8 __attribute__((ext_vector_type(8)));
typedef float f32x4 __attribute__((ext_vector_type(4)));

__device__ __forceinline__ f32x4 MFMA16(bf16x8 a, bf16x8 b, f32x4 c) {
  return __builtin_amdgcn_mfma_f32_16x16x32_bf16(a, b, c, 0, 0, 0);
}

__device__ __forceinline__ bf16 split_hi(float v) { return (bf16)v; }
__device__ __forceinline__ bf16 split_lo(float v) { return (bf16)(v - (float)(bf16)v); }

// ---- f32 -> bf16 bulk convert ----
__global__ void k_cvt(const float* __restrict__ in, bf16* __restrict__ out, long n) {
  const long i = ((long)blockIdx.x * 256 + threadIdx.x) * 4;
  if (i < n) {
    const f32x4 v = *(const f32x4*)&in[i];
    bf16x4 o;
#pragma unroll
    for (int j = 0; j < 4; ++j) o[j] = (bf16)v[j];
    *(bf16x4*)&out[i] = o;
  }
}

// ---- Wc[b][d][r] = sum_k w[b,k] * neurons[idx[b,k]][d][r]  (f32 out) ----
__global__ void k_build_wc(const float* __restrict__ neurons, const float* __restrict__ w,
                           const int* __restrict__ idx, float* __restrict__ Wc) {
  const int d = blockIdx.x, b = blockIdx.y, r = threadIdx.x;
  float acc = 0.f;
#pragma unroll
  for (int k = 0; k < 16; ++k) {
    const float wk = w[b * 16 + k];
    const int ni = idx[b * 16 + k];
    acc += wk * neurons[((long)ni * 1024 + d) * 128 + r];
  }
  Wc[((long)b * 1024 + d) * 128 + r] = acc;
}

// ---- Wn[z=which*8+b][r][d] = sum_k w[b,k] * pool[idx[b,k]][r][d]  (f32 out) ----
__global__ void k_build_mix(const float* __restrict__ pool,
                            const float* __restrict__ wq, const int* __restrict__ iq,
                            const float* __restrict__ wk, const int* __restrict__ ik,
                            const float* __restrict__ wv, const int* __restrict__ iv,
                            float* __restrict__ Wn) {
  const int d = blockIdx.x * 256 + threadIdx.x;
  const int r = blockIdx.y;
  const int z = blockIdx.z, which = z >> 3, b = z & 7;
  const float* wp = which == 0 ? wq : (which == 1 ? wk : wv);
  const int* ip = which == 0 ? iq : (which == 1 ? ik : iv);
  float acc = 0.f;
#pragma unroll
  for (int k = 0; k < 8; ++k) {
    const float wkk = wp[b * 8 + k];
    const int ni = ip[b * 8 + k];
    acc += wkk * pool[((long)ni * 128 + r) * 1024 + d];
  }
  Wn[((long)z * 128 + r) * 1024 + d] = acc;
}

// ---- batched transpose [M][N] -> [N][M] (z = batch) ----
template <typename T>
__global__ void k_transpose(const T* __restrict__ in, T* __restrict__ out, int M, int N) {
  __shared__ T t[64][65];
  const int n0 = blockIdx.x * 64, m0 = blockIdx.y * 64;
  const long base = (long)blockIdx.z * M * N;
  const int tid = threadIdx.x;
#pragma unroll
  for (int i = 0; i < 16; ++i) {
    const int lin = i * 256 + tid;
    const int r = lin >> 6, c = lin & 63;
    t[r][c] = in[base + (long)(m0 + r) * N + (n0 + c)];
  }
  __syncthreads();
#pragma unroll
  for (int i = 0; i < 16; ++i) {
    const int lin = i * 256 + tid;
    const int r = lin >> 6, c = lin & 63;
    out[base + (long)(n0 + r) * M + (m0 + c)] = t[c][r];
  }
}

// ---- GEMM: C = A(MxK,f32) * Bt[n][k](f32), scaled.
// SPLIT: hi/lo bf16 split inputs, 3 MFMAs/tile (~fp32); else plain bf16, 1 MFMA.
// mode: 0 = bf16 out, 1 = f32 out, 2 = split-pair bf16 out (C=hi, C2=lo).
// split_heads: C[(col/64)][row][col%64]. 4 waves 2x2.
template <int BM, int BN, bool SPLIT>
__global__ __launch_bounds__(256) void k_gemm_split(
    const float* __restrict__ A, const float* __restrict__ Bt, void* __restrict__ C,
    bf16* __restrict__ C2, int M, int N, int K, long sA, long sB, long sC,
    int split_heads, int mode, float scale) {
  constexpr int BK = 32, LDR = 40;
  constexpr int MT = BM / 32, NT = BN / 32;
  __shared__ __align__(16) bf16 Ash[BM * LDR];
  __shared__ __align__(16) bf16 Bsh[BN * LDR];
  __shared__ __align__(16) bf16 Asl[SPLIT ? BM * LDR : 1];
  __shared__ __align__(16) bf16 Bsl[SPLIT ? BN * LDR : 1];
  const int tid = threadIdx.x, wave = tid >> 6, lane = tid & 63;
  const int quad = lane >> 4, l16 = lane & 15;
  const int wrow = wave >> 1, wcol = wave & 1;
  const int z = blockIdx.z;
  const float* Ap = A + (long)z * sA;
  const float* Bp = Bt + (long)z * sB;
  const long m0 = (long)blockIdx.y * BM, n0 = (long)blockIdx.x * BN;
  f32x4 acc[MT][NT];
#pragma unroll
  for (int mt = 0; mt < MT; ++mt)
#pragma unroll
    for (int nt = 0; nt < NT; ++nt) acc[mt][nt] = (f32x4){0.f, 0.f, 0.f, 0.f};
  for (int k0 = 0; k0 < K; k0 += BK) {
#pragma unroll
    for (int i = 0; i < BM / 32; ++i) {
      const int c = i * 256 + tid, r = c >> 3, c4 = c & 7;
      const f32x4 v = *(const f32x4*)&Ap[(m0 + r) * K + k0 + c4 * 4];
      bf16x4 h4, l4;
#pragma unroll
      for (int j = 0; j < 4; ++j) { h4[j] = split_hi(v[j]); l4[j] = split_lo(v[j]); }
      *(bf16x4*)&Ash[r * LDR + c4 * 4] = h4;
      if (SPLIT) *(bf16x4*)&Asl[r * LDR + c4 * 4] = l4;
    }
#pragma unroll
    for (int i = 0; i < BN / 32; ++i) {
      const int c = i * 256 + tid, r = c >> 3, c4 = c & 7;
      const f32x4 v = *(const f32x4*)&Bp[(n0 + r) * K + k0 + c4 * 4];
      bf16x4 h4, l4;
#pragma unroll
      for (int j = 0; j < 4; ++j) { h4[j] = split_hi(v[j]); l4[j] = split_lo(v[j]); }
      *(bf16x4*)&Bsh[r * LDR + c4 * 4] = h4;
      if (SPLIT) *(bf16x4*)&Bsl[r * LDR + c4 * 4] = l4;
    }
    __syncthreads();
    bf16x8 ah[MT], al[MT], bh[NT], bl[NT];
#pragma unroll
    for (int mt = 0; mt < MT; ++mt) {
      const int row = wrow * (MT * 16) + mt * 16 + l16;
      ah[mt] = *(const bf16x8*)&Ash[row * LDR + quad * 8];
      if (SPLIT) al[mt] = *(const bf16x8*)&Asl[row * LDR + quad * 8];
    }
#pragma unroll
    for (int nt = 0; nt < NT; ++nt) {
      const int row = wcol * (NT * 16) + nt * 16 + l16;
      bh[nt] = *(const bf16x8*)&Bsh[row * LDR + quad * 8];
      if (SPLIT) bl[nt] = *(const bf16x8*)&Bsl[row * LDR + quad * 8];
    }
#pragma unroll
    for (int mt = 0; mt < MT; ++mt)
#pragma unroll
      for (int nt = 0; nt < NT; ++nt) {
        acc[mt][nt] = MFMA16(ah[mt], bh[nt], acc[mt][nt]);
        if (SPLIT) {
          acc[mt][nt] = MFMA16(ah[mt], bl[nt], acc[mt][nt]);
          acc[mt][nt] = MFMA16(al[mt], bh[nt], acc[mt][nt]);
        }
      }
    __syncthreads();
  }
  bf16* Cb = (bf16*)C + (long)z * sC;
  float* Cf = (float*)C + (long)z * sC;
  bf16* C2b = C2 + (long)z * sC;
#pragma unroll
  for (int mt = 0; mt < MT; ++mt)
#pragma unroll
    for (int nt = 0; nt < NT; ++nt)
#pragma unroll
      for (int r = 0; r < 4; ++r) {
        const long row = m0 + wrow * (MT * 16) + mt * 16 + quad * 4 + r;
        const long col = n0 + wcol * (NT * 16) + nt * 16 + l16;
        const float v = acc[mt][nt][r] * scale;
        const long off = split_heads
                             ? ((col >> 6) * ((long)M * 64) + row * 64 + (col & 63))
                             : (row * (long)N + col);
        if (mode == 1) {
          Cf[off] = v;
        } else if (mode == 0) {
          Cb[off] = (bf16)v;
        } else {
          const bf16 hi = (bf16)v;
          Cb[off] = hi;
          C2b[off] = (bf16)(v - (float)hi);
        }
      }
}

// ---- plain bf16 GEMM (output projection): C = A(MxK) * Bt[n][k], out f32. ----
template <int BM, int BN>
__global__ __launch_bounds__(256) void k_gemm_bt(
    const bf16* __restrict__ A, const bf16* __restrict__ Bt, float* __restrict__ C,
    int M, int N, int K) {
  constexpr int BK = 32, LDR = BK + 8;
  constexpr int MT = BM / 32, NT = BN / 32;
  __shared__ __align__(16) bf16 As[BM * LDR];
  __shared__ __align__(16) bf16 Bs[BN * LDR];
  const int tid = threadIdx.x, wave = tid >> 6, lane = tid & 63;
  const int quad = lane >> 4, l16 = lane & 15;
  const int wrow = wave >> 1, wcol = wave & 1;
  const long m0 = (long)blockIdx.y * BM, n0 = (long)blockIdx.x * BN;
  f32x4 acc[MT][NT];
#pragma unroll
  for (int mt = 0; mt < MT; ++mt)
#pragma unroll
    for (int nt = 0; nt < NT; ++nt) acc[mt][nt] = (f32x4){0.f, 0.f, 0.f, 0.f};
  constexpr int ACH = BM * BK / 8 / 256;
  constexpr int BCH = BN * BK / 8 / 256;
  for (int k0 = 0; k0 < K; k0 += BK) {
#pragma unroll
    for (int i = 0; i < ACH; ++i) {
      const int c = i * 256 + tid, r = c >> 2, c4 = c & 3;
      *(bf16x8*)&As[r * LDR + c4 * 8] = *(const bf16x8*)&A[(m0 + r) * K + k0 + c4 * 8];
    }
#pragma unroll
    for (int i = 0; i < BCH; ++i) {
      const int c = i * 256 + tid, r = c >> 2, c4 = c & 3;
      *(bf16x8*)&Bs[r * LDR + c4 * 8] = *(const bf16x8*)&Bt[(n0 + r) * K + k0 + c4 * 8];
    }
    __syncthreads();
    bf16x8 af[MT], bfr[NT];
#pragma unroll
    for (int mt = 0; mt < MT; ++mt)
      af[mt] = *(const bf16x8*)&As[(wrow * MT * 16 + mt * 16 + l16) * LDR + quad * 8];
#pragma unroll
    for (int nt = 0; nt < NT; ++nt)
      bfr[nt] = *(const bf16x8*)&Bs[(wcol * NT * 16 + nt * 16 + l16) * LDR + quad * 8];
#pragma unroll
    for (int mt = 0; mt < MT; ++mt)
#pragma unroll
      for (int nt = 0; nt < NT; ++nt)
        acc[mt][nt] = MFMA16(af[mt], bfr[nt], acc[mt][nt]);
    __syncthreads();
  }
#pragma unroll
  for (int mt = 0; mt < MT; ++mt)
#pragma unroll
    for (int nt = 0; nt < NT; ++nt)
#pragma unroll
      for (int r = 0; r < 4; ++r) {
        const long row = m0 + wrow * MT * 16 + mt * 16 + quad * 4 + r;
        const long col = n0 + wcol * NT * 16 + nt * 16 + l16;
        C[row * (long)N + col] = acc[mt][nt][r];
      }
}

// ---- causal flash attention, paired q-tiles, double-buffered staging,
// log2-domain softmax (Q pre-scaled by log2e/8), MFMA row-sums for l_i.
// Qhi/Qlo/Khi/Klo: [B*H][S][64] bf16. Vt: [B*H][64][S] bf16.
// Out att: [B][S][1024] bf16. Block p handles q-tiles p and 7-p (128 rows each).
__global__ __launch_bounds__(256) void k_attn(
    const bf16* __restrict__ Qhi, const bf16* __restrict__ Qlo,
    const bf16* __restrict__ Khi, const bf16* __restrict__ Klo,
    const bf16* __restrict__ Vtg, bf16* __restrict__ Og) {
  __shared__ __align__(16) bf16 KhiS[2 * 64 * 72], KloS[2 * 64 * 72];
  __shared__ __align__(16) bf16 VtS[2 * 64 * 72];
  __shared__ __align__(16) bf16 Ps[4 * 32 * 72];  // per-wave P
  const int p = blockIdx.x, bh = blockIdx.y;
  const int b = bh >> 4, hh = bh & 15;
  const int tid = threadIdx.x, wave = tid >> 6, lane = tid & 63;
  const int quad = lane >> 4, l16 = lane & 15;
  const long bhS = (long)bh * 1024 * 64;
  const bf16* KhiG = Khi + bhS;
  const bf16* KloG = Klo + bhS;
  const bf16* VtG = Vtg + (long)bh * 64 * 1024;
  const int qbwA = p * 128 + wave * 32;
  const int qbwB = (7 - p) * 128 + wave * 32;
  bf16x8 qhA[2][2], qlA[2][2], qhB[2][2], qlB[2][2];
#pragma unroll
  for (int m = 0; m < 2; ++m) {
    const long rA = (long)(qbwA + m * 16 + l16) * 64;
    const long rB = (long)(qbwB + m * 16 + l16) * 64;
#pragma unroll
    for (int s = 0; s < 2; ++s) {
      qhA[m][s] = *(const bf16x8*)&Qhi[bhS + rA + s * 32 + quad * 8];
      qlA[m][s] = *(const bf16x8*)&Qlo[bhS + rA + s * 32 + quad * 8];
      qhB[m][s] = *(const bf16x8*)&Qhi[bhS + rB + s * 32 + quad * 8];
      qlB[m][s] = *(const bf16x8*)&Qlo[bhS + rB + s * 32 + quad * 8];
    }
  }
  bf16x8 ones8;
#pragma unroll
  for (int j = 0; j < 8; ++j) ones8[j] = (bf16)1.0f;
  const f32x4 zero4 = {0.f, 0.f, 0.f, 0.f};
  f32x4 oA[2][4], oB[2][4];
  float mA[2][4], lA[2][4], mB[2][4], lB[2][4];
#pragma unroll
  for (int m = 0; m < 2; ++m)
#pragma unroll
    for (int r = 0; r < 4; ++r) {
      mA[m][r] = -1.0e30f; lA[m][r] = 0.f;
      mB[m][r] = -1.0e30f; lB[m][r] = 0.f;
    }
#pragma unroll
  for (int m = 0; m < 2; ++m)
#pragma unroll
    for (int nt = 0; nt < 4; ++nt) { oA[m][nt] = zero4; oB[m][nt] = zero4; }

  bf16x8 sKh[2], sKl[2], sVt[2];  // staging registers
  auto load_regs = [&](int kc) {
    const int kb = kc * 64;
#pragma unroll
    for (int i = 0; i < 2; ++i) {
      const int c = i * 256 + tid, r = c >> 3, c8 = c & 7;
      sKh[i] = *(const bf16x8*)&KhiG[(long)(kb + r) * 64 + c8 * 8];
      sKl[i] = *(const bf16x8*)&KloG[(long)(kb + r) * 64 + c8 * 8];
      sVt[i] = *(const bf16x8*)&VtG[(long)r * 1024 + kb + c8 * 8];
    }
  };
  auto write_lds = [&](int buf) {
    const int o = buf * 64 * 72;
#pragma unroll
    for (int i = 0; i < 2; ++i) {
      const int c = i * 256 + tid, r = c >> 3, c8 = c & 7;
      *(bf16x8*)&KhiS[o + r * 72 + c8 * 8] = sKh[i];
      *(bf16x8*)&KloS[o + r * 72 + c8 * 8] = sKl[i];
      *(bf16x8*)&VtS[o + r * 72 + c8 * 8] = sVt[i];
    }
  };
  auto tile_compute = [&](const bf16x8 (&qh)[2][2], const bf16x8 (&ql)[2][2],
                          f32x4 (&o)[2][4], float (&m_i)[2][4], float (&l_i)[2][4],
                          int qbw, int kb, int buf) {
    const int ob = buf * 64 * 72;
    f32x4 sc[2][4];
#pragma unroll
    for (int ct = 0; ct < 4; ++ct) {
      const int krow = ob + (ct * 16 + l16) * 72;
      const bf16x8 kh0 = *(const bf16x8*)&KhiS[krow + quad * 8];
      const bf16x8 kh1 = *(const bf16x8*)&KhiS[krow + 32 + quad * 8];
      const bf16x8 kl0 = *(const bf16x8*)&KloS[krow + quad * 8];
      const bf16x8 kl1 = *(const bf16x8*)&KloS[krow + 32 + quad * 8];
#pragma unroll
      for (int m = 0; m < 2; ++m) {
        f32x4 s = MFMA16(qh[m][0], kh0, zero4);
        s = MFMA16(qh[m][1], kh1, s);
        s = MFMA16(qh[m][0], kl0, s);
        s = MFMA16(qh[m][1], kl1, s);
        s = MFMA16(ql[m][0], kh0, s);
        s = MFMA16(ql[m][1], kh1, s);
        sc[m][ct] = s;
      }
    }
    if (kb + 63 > qbw) {  // diagonal region: causal mask
#pragma unroll
      for (int ct = 0; ct < 4; ++ct) {
        const int col = kb + ct * 16 + l16;
#pragma unroll
        for (int m = 0; m < 2; ++m)
#pragma unroll
          for (int r = 0; r < 4; ++r) {
            const int row = qbw + m * 16 + quad * 4 + r;
            if (col > row) sc[m][ct][r] = -1.0e30f;
          }
      }
    }
    bf16x8 ap[2][2];
    float alpha[2][4];
#pragma unroll
    for (int m = 0; m < 2; ++m) {
      float rmax[4];
#pragma unroll
      for (int r = 0; r < 4; ++r)
        rmax[r] = fmaxf(fmaxf(sc[m][0][r], sc[m][1][r]), fmaxf(sc[m][2][r], sc[m][3][r]));
#pragma unroll
      for (int off = 1; off < 16; off <<= 1)
#pragma unroll
        for (int r = 0; r < 4; ++r) rmax[r] = fmaxf(rmax[r], __shfl_xor(rmax[r], off));
#pragma unroll
      for (int r = 0; r < 4; ++r) {
        const float mnew = fmaxf(m_i[m][r], rmax[r]);
        alpha[m][r] = __builtin_amdgcn_exp2f(m_i[m][r] - mnew);  // log2 domain
        m_i[m][r] = mnew;
      }
#pragma unroll
      for (int ct = 0; ct < 4; ++ct)
#pragma unroll
        for (int r = 0; r < 4; ++r)
          Ps[wave * 2304 + (m * 16 + quad * 4 + r) * 72 + ct * 16 + l16] =
              (bf16)__builtin_amdgcn_exp2f(sc[m][ct][r] - m_i[m][r]);
      ap[m][0] = *(const bf16x8*)&Ps[wave * 2304 + (m * 16 + l16) * 72 + quad * 8];
      ap[m][1] = *(const bf16x8*)&Ps[wave * 2304 + (m * 16 + l16) * 72 + 32 + quad * 8];
      // l_i row-sums via MFMA with all-ones B (C-layout rows match m_i/l_i rows)
      f32x4 rs = MFMA16(ap[m][0], ones8, zero4);
      rs = MFMA16(ap[m][1], ones8, rs);
#pragma unroll
      for (int r = 0; r < 4; ++r) l_i[m][r] = l_i[m][r] * alpha[m][r] + rs[r];
#pragma unroll
      for (int nt = 0; nt < 4; ++nt)
#pragma unroll
        for (int r = 0; r < 4; ++r) o[m][nt][r] *= alpha[m][r];
    }
#pragma unroll
    for (int nt = 0; nt < 4; ++nt) {
      const bf16x8 bv0 = *(const bf16x8*)&VtS[ob + (nt * 16 + l16) * 72 + quad * 8];
      const bf16x8 bv1 = *(const bf16x8*)&VtS[ob + (nt * 16 + l16) * 72 + 32 + quad * 8];
#pragma unroll
      for (int m = 0; m < 2; ++m) {
        o[m][nt] = MFMA16(ap[m][0], bv0, o[m][nt]);
        o[m][nt] = MFMA16(ap[m][1], bv1, o[m][nt]);
      }
    }
  };

  const int nch = 2 * (7 - p) + 2;
  load_regs(0);
  write_lds(0);
  __syncthreads();
  for (int kc = 0; kc < nch; ++kc) {
    const int kb = kc * 64;
    const int buf = kc & 1;
    if (kc + 1 < nch) load_regs(kc + 1);  // prefetch next chunk (latency hidden)
    if (kb <= qbwA + 31) tile_compute(qhA, qlA, oA, mA, lA, qbwA, kb, buf);
    if (kb <= qbwB + 31) tile_compute(qhB, qlB, oB, mB, lB, qbwB, kb, buf);
    if (kc + 1 < nch) write_lds(1 - buf);
    __syncthreads();
  }
#pragma unroll
  for (int t = 0; t < 2; ++t) {
    const int qbw = t ? qbwB : qbwA;
#pragma unroll
    for (int m = 0; m < 2; ++m) {
      float inv[4];
#pragma unroll
      for (int r = 0; r < 4; ++r) inv[r] = 1.f / (t ? lB[m][r] : lA[m][r]);
#pragma unroll
      for (int nt = 0; nt < 4; ++nt)
#pragma unroll
        for (int r = 0; r < 4; ++r) {
          const int row = qbw + m * 16 + quad * 4 + r;
          const float v = (t ? oB[m][nt][r] : oA[m][nt][r]) * inv[r];
          Og[((long)b * 1024 + row) * 1024 + hh * 64 + nt * 16 + l16] = (bf16)v;
        }
    }
  }
}

extern "C" void kernel_launch(void* const* d_in, const int* in_sizes, int n_in,
                              void* d_out, int out_size, void* d_ws, size_t ws_size,
                              hipStream_t stream) {
  const float* x = (const float*)d_in[0];
  const float* cw = (const float*)d_in[1];
  const int* cidx = (const int*)d_in[2];
  const float* wq = (const float*)d_in[3];
  const int* iq = (const int*)d_in[4];
  const float* wk = (const float*)d_in[5];
  const int* ik = (const int*)d_in[6];
  const float* wv = (const float*)d_in[7];
  const int* iv = (const int*)d_in[8];
  const float* neurons = (const float*)d_in[9];
  const float* pool = (const float*)d_in[10];
  const float* WO = (const float*)d_in[11];
  float* out = (float*)d_out;
  char* ws = (char*)d_ws;
  // Workspace (86 MB peak, lifetime-overlapped):
  //   [ 0,16) Khi bf16 | [16,32) Klo bf16 | [32,48) Vt bf16 [8][16][64][1024]
  //   [48,64) att bf16  -- prep overlay: Wc f32 [48,52), Wn f32 [52,64)
  //   [64,68) WcT f32 | [68,80) Wt f32 [24][1024][128] | [80,84) h f32 | [84,86) WOb
  //   Qhi/Qlo bf16 in d_out (2 x 16 MB), dead before the final f32 write.
  bf16* Khi = (bf16*)(ws + (0l << 20));
  bf16* Klo = (bf16*)(ws + (16l << 20));
  bf16* Vt = (bf16*)(ws + (32l << 20));
  bf16* att = (bf16*)(ws + (48l << 20));
  float* Wc = (float*)(ws + (48l << 20));
  float* Wn = (float*)(ws + (52l << 20));
  float* WcT = (float*)(ws + (64l << 20));
  float* Wt = (float*)(ws + (68l << 20));
  float* h = (float*)(ws + (80l << 20));
  bf16* WOb = (bf16*)(ws + (84l << 20));
  bf16* Qhi = (bf16*)d_out;
  bf16* Qlo = (bf16*)d_out + (8l << 20);

  k_cvt<<<1024, 256, 0, stream>>>(WO, WOb, 1024l * 1024);
  k_build_wc<<<dim3(1024, 8), 128, 0, stream>>>(neurons, cw, cidx, Wc);
  k_build_mix<<<dim3(4, 128, 24), 256, 0, stream>>>(pool, wq, iq, wk, ik, wv, iv, Wn);
  k_transpose<float><<<dim3(2, 16, 8), 256, 0, stream>>>(Wc, WcT, 1024, 128);
  k_transpose<float><<<dim3(16, 2, 24), 256, 0, stream>>>(Wn, Wt, 128, 1024);
  // h[b] = x[b] (1024x1024) * Wc[b] (1024x128), split-precision, f32 out
  k_gemm_split<64, 64, true><<<dim3(2, 16, 8), 256, 0, stream>>>(
      x, WcT, h, nullptr, 1024, 128, 1024, 1l << 20, 1l << 17, 1l << 17, 0, 1, 1.f);
  // Q = (h*Wq) * (log2e/8), pre-split into Qhi/Qlo (head-split layout)
  k_gemm_split<64, 64, true><<<dim3(16, 16, 8), 256, 0, stream>>>(
      h, Wt, Qhi, Qlo, 1024, 1024, 128, 1l << 17, 1l << 17, 1l << 20, 1, 2,
      0.125f * 1.44269504088896f);
  // K pre-split into Khi/Klo (head-split layout)
  k_gemm_split<64, 64, true><<<dim3(16, 16, 8), 256, 0, stream>>>(
      h, Wt + (8l << 17), Khi, Klo, 1024, 1024, 128, 1l << 17, 1l << 17, 1l << 20, 1, 2, 1.f);
  // V^T directly, plain bf16 (V is bf16-rounded anyway): Vt[z] = Wt_V[z] * h[z]^T
  k_gemm_split<64, 64, false><<<dim3(16, 16, 8), 256, 0, stream>>>(
      Wt + (16l << 17), h, Vt, nullptr, 1024, 1024, 128, 1l << 17, 1l << 17, 1l << 20, 0, 0, 1.f);
  k_attn<<<dim3(4, 128), 256, 0, stream>>>(Qhi, Qlo, Khi, Klo, Vt, att);
  // out(f32, 8192x1024) = att * W_O^T (W_O [d_out][d_in] is already Bt layout)
  k_gemm_bt<128, 128><<<dim3(8, 64, 1), 256, 0, stream>>>(att, WOb, out, 8192, 1024, 1024);
}

// Round 10
// 375.103 us; speedup vs baseline: 1.1029x; 1.0380x over previous
//
#include <hip/hip_runtime.h>

typedef __bf16 bf16;
typedef __bf16 bf16x4 __attribute__((ext_vector_type(4)));
typedef __bf16 bf16x8 __attribute__((ext_vector_type(8)));
typedef float f32x4 __attribute__((ext_vector_type(4)));

__device__ __forceinline__ f32x4 MFMA16(bf16x8 a, bf16x8 b, f32x4 c) {
  return __builtin_amdgcn_mfma_f32_16x16x32_bf16(a, b, c, 0, 0, 0);
}

__device__ __forceinline__ bf16 split_hi(float v) { return (bf16)v; }
__device__ __forceinline__ bf16 split_lo(float v) { return (bf16)(v - (float)(bf16)v); }

// ---- f32 -> bf16 bulk convert ----
__global__ void k_cvt(const float* __restrict__ in, bf16* __restrict__ out, long n) {
  const long i = ((long)blockIdx.x * 256 + threadIdx.x) * 4;
  if (i < n) {
    const f32x4 v = *(const f32x4*)&in[i];
    bf16x4 o;
#pragma unroll
    for (int j = 0; j < 4; ++j) o[j] = (bf16)v[j];
    *(bf16x4*)&out[i] = o;
  }
}

// ---- Wc[b][d][r] = sum_k w[b,k] * neurons[idx[b,k]][d][r]  (f32 out) ----
__global__ void k_build_wc(const float* __restrict__ neurons, const float* __restrict__ w,
                           const int* __restrict__ idx, float* __restrict__ Wc) {
  const int d = blockIdx.x, b = blockIdx.y, r = threadIdx.x;
  float acc = 0.f;
#pragma unroll
  for (int k = 0; k < 16; ++k) {
    const float wk = w[b * 16 + k];
    const int ni = idx[b * 16 + k];
    acc += wk * neurons[((long)ni * 1024 + d) * 128 + r];
  }
  Wc[((long)b * 1024 + d) * 128 + r] = acc;
}

// ---- Wn[z=which*8+b][r][d] = sum_k w[b,k] * pool[idx[b,k]][r][d]  (f32 out) ----
__global__ void k_build_mix(const float* __restrict__ pool,
                            const float* __restrict__ wq, const int* __restrict__ iq,
                            const float* __restrict__ wk, const int* __restrict__ ik,
                            const float* __restrict__ wv, const int* __restrict__ iv,
                            float* __restrict__ Wn) {
  const int d = blockIdx.x * 256 + threadIdx.x;
  const int r = blockIdx.y;
  const int z = blockIdx.z, which = z >> 3, b = z & 7;
  const float* wp = which == 0 ? wq : (which == 1 ? wk : wv);
  const int* ip = which == 0 ? iq : (which == 1 ? ik : iv);
  float acc = 0.f;
#pragma unroll
  for (int k = 0; k < 8; ++k) {
    const float wkk = wp[b * 8 + k];
    const int ni = ip[b * 8 + k];
    acc += wkk * pool[((long)ni * 128 + r) * 1024 + d];
  }
  Wn[((long)z * 128 + r) * 1024 + d] = acc;
}

// ---- batched transpose f32 [M][N] -> split bf16 pair [N][M] ----
__global__ void k_transpose_split(const float* __restrict__ in, bf16* __restrict__ outh,
                                  bf16* __restrict__ outl, int M, int N) {
  __shared__ float t[64][65];
  const int n0 = blockIdx.x * 64, m0 = blockIdx.y * 64;
  const long base = (long)blockIdx.z * M * N;
  const int tid = threadIdx.x;
#pragma unroll
  for (int i = 0; i < 16; ++i) {
    const int lin = i * 256 + tid;
    const int r = lin >> 6, c = lin & 63;
    t[r][c] = in[base + (long)(m0 + r) * N + (n0 + c)];
  }
  __syncthreads();
#pragma unroll
  for (int i = 0; i < 16; ++i) {
    const int lin = i * 256 + tid;
    const int r = lin >> 6, c = lin & 63;
    const float v = t[c][r];
    const long off = base + (long)(n0 + r) * M + (m0 + c);
    outh[off] = split_hi(v);
    outl[off] = split_lo(v);
  }
}

// ---- h-GEMM: A f32 (split in-kernel), Bt pre-split bf16 pair; out split-pair.
// A [M][K] f32, Bt[n][k] pair. M=1024 N=128 K=1024. BM=BN=64, 4 waves 2x2.
__global__ __launch_bounds__(256) void k_gemm_h(
    const float* __restrict__ A, const bf16* __restrict__ Bth,
    const bf16* __restrict__ Btl, bf16* __restrict__ Ch, bf16* __restrict__ Cl,
    int M, int N, int K, long sA, long sB, long sC) {
  constexpr int LDR = 40;
  __shared__ __align__(16) bf16 Ash[64 * LDR], Asl[64 * LDR];
  __shared__ __align__(16) bf16 Bsh[64 * LDR], Bsl[64 * LDR];
  const int tid = threadIdx.x, wave = tid >> 6, lane = tid & 63;
  const int quad = lane >> 4, l16 = lane & 15;
  const int wrow = wave >> 1, wcol = wave & 1;
  const int z = blockIdx.z;
  const float* Ap = A + (long)z * sA;
  const bf16* Bph = Bth + (long)z * sB;
  const bf16* Bpl = Btl + (long)z * sB;
  const long m0 = (long)blockIdx.y * 64, n0 = (long)blockIdx.x * 64;
  f32x4 acc[2][2];
#pragma unroll
  for (int mt = 0; mt < 2; ++mt)
#pragma unroll
    for (int nt = 0; nt < 2; ++nt) acc[mt][nt] = (f32x4){0.f, 0.f, 0.f, 0.f};
  for (int k0 = 0; k0 < K; k0 += 32) {
#pragma unroll
    for (int i = 0; i < 2; ++i) {
      const int c = i * 256 + tid, r = c >> 3, c4 = c & 7;
      const f32x4 v = *(const f32x4*)&Ap[(m0 + r) * K + k0 + c4 * 4];
      bf16x4 h4, l4;
#pragma unroll
      for (int j = 0; j < 4; ++j) { h4[j] = split_hi(v[j]); l4[j] = split_lo(v[j]); }
      *(bf16x4*)&Ash[r * LDR + c4 * 4] = h4;
      *(bf16x4*)&Asl[r * LDR + c4 * 4] = l4;
    }
    {
      const int r = tid >> 2, c8 = tid & 3;
      *(bf16x8*)&Bsh[r * LDR + c8 * 8] = *(const bf16x8*)&Bph[(n0 + r) * K + k0 + c8 * 8];
      *(bf16x8*)&Bsl[r * LDR + c8 * 8] = *(const bf16x8*)&Bpl[(n0 + r) * K + k0 + c8 * 8];
    }
    __syncthreads();
    bf16x8 ah[2], al[2], bh[2], bl[2];
#pragma unroll
    for (int mt = 0; mt < 2; ++mt) {
      const int row = wrow * 32 + mt * 16 + l16;
      ah[mt] = *(const bf16x8*)&Ash[row * LDR + quad * 8];
      al[mt] = *(const bf16x8*)&Asl[row * LDR + quad * 8];
    }
#pragma unroll
    for (int nt = 0; nt < 2; ++nt) {
      const int row = wcol * 32 + nt * 16 + l16;
      bh[nt] = *(const bf16x8*)&Bsh[row * LDR + quad * 8];
      bl[nt] = *(const bf16x8*)&Bsl[row * LDR + quad * 8];
    }
#pragma unroll
    for (int mt = 0; mt < 2; ++mt)
#pragma unroll
      for (int nt = 0; nt < 2; ++nt) {
        acc[mt][nt] = MFMA16(ah[mt], bh[nt], acc[mt][nt]);
        acc[mt][nt] = MFMA16(ah[mt], bl[nt], acc[mt][nt]);
        acc[mt][nt] = MFMA16(al[mt], bh[nt], acc[mt][nt]);
      }
    __syncthreads();
  }
#pragma unroll
  for (int mt = 0; mt < 2; ++mt)
#pragma unroll
    for (int nt = 0; nt < 2; ++nt)
#pragma unroll
      for (int r = 0; r < 4; ++r) {
        const long row = m0 + wrow * 32 + mt * 16 + quad * 4 + r;
        const long col = n0 + wcol * 32 + nt * 16 + l16;
        const float v = acc[mt][nt][r];
        const long off = (long)z * sC + row * (long)N + col;
        const bf16 hi = (bf16)v;
        Ch[off] = hi;
        Cl[off] = (bf16)(v - (float)hi);
      }
}

// ---- dual-bf16 GEMM: A pair [M][K], Bt pair [N][K] (both pre-split).
// SPLIT: 3 MFMAs (hh+hl+lh); else hi-only, 1 MFMA.
// mode: 0 = bf16 out, 2 = split-pair out. split_heads: C[(col/64)][row][col%64].
template <bool SPLIT>
__global__ __launch_bounds__(256) void k_gemm_dual(
    const bf16* __restrict__ Ah, const bf16* __restrict__ Al,
    const bf16* __restrict__ Bth, const bf16* __restrict__ Btl,
    bf16* __restrict__ C, bf16* __restrict__ C2, int M, int N, int K,
    long sA, long sB, long sC, int split_heads, int mode, float scale) {
  constexpr int LDR = 40;
  __shared__ __align__(16) bf16 Ash[64 * LDR], Bsh[64 * LDR];
  __shared__ __align__(16) bf16 Asl[SPLIT ? 64 * LDR : 1];
  __shared__ __align__(16) bf16 Bsl[SPLIT ? 64 * LDR : 1];
  const int tid = threadIdx.x, wave = tid >> 6, lane = tid & 63;
  const int quad = lane >> 4, l16 = lane & 15;
  const int wrow = wave >> 1, wcol = wave & 1;
  const int z = blockIdx.z;
  const bf16* Aph = Ah + (long)z * sA;
  const bf16* Apl = Al + (long)z * sA;
  const bf16* Bph = Bth + (long)z * sB;
  const bf16* Bpl = Btl + (long)z * sB;
  const long m0 = (long)blockIdx.y * 64, n0 = (long)blockIdx.x * 64;
  f32x4 acc[2][2];
#pragma unroll
  for (int mt = 0; mt < 2; ++mt)
#pragma unroll
    for (int nt = 0; nt < 2; ++nt) acc[mt][nt] = (f32x4){0.f, 0.f, 0.f, 0.f};
  for (int k0 = 0; k0 < K; k0 += 32) {
    {
      const int r = tid >> 2, c8 = tid & 3;
      *(bf16x8*)&Ash[r * LDR + c8 * 8] = *(const bf16x8*)&Aph[(m0 + r) * K + k0 + c8 * 8];
      if (SPLIT)
        *(bf16x8*)&Asl[r * LDR + c8 * 8] = *(const bf16x8*)&Apl[(m0 + r) * K + k0 + c8 * 8];
      *(bf16x8*)&Bsh[r * LDR + c8 * 8] = *(const bf16x8*)&Bph[(n0 + r) * K + k0 + c8 * 8];
      if (SPLIT)
        *(bf16x8*)&Bsl[r * LDR + c8 * 8] = *(const bf16x8*)&Bpl[(n0 + r) * K + k0 + c8 * 8];
    }
    __syncthreads();
    bf16x8 ah[2], al[2], bh[2], bl[2];
#pragma unroll
    for (int mt = 0; mt < 2; ++mt) {
      const int row = wrow * 32 + mt * 16 + l16;
      ah[mt] = *(const bf16x8*)&Ash[row * LDR + quad * 8];
      if (SPLIT) al[mt] = *(const bf16x8*)&Asl[row * LDR + quad * 8];
    }
#pragma unroll
    for (int nt = 0; nt < 2; ++nt) {
      const int row = wcol * 32 + nt * 16 + l16;
      bh[nt] = *(const bf16x8*)&Bsh[row * LDR + quad * 8];
      if (SPLIT) bl[nt] = *(const bf16x8*)&Bsl[row * LDR + quad * 8];
    }
#pragma unroll
    for (int mt = 0; mt < 2; ++mt)
#pragma unroll
      for (int nt = 0; nt < 2; ++nt) {
        acc[mt][nt] = MFMA16(ah[mt], bh[nt], acc[mt][nt]);
        if (SPLIT) {
          acc[mt][nt] = MFMA16(ah[mt], bl[nt], acc[mt][nt]);
          acc[mt][nt] = MFMA16(al[mt], bh[nt], acc[mt][nt]);
        }
      }
    __syncthreads();
  }
#pragma unroll
  for (int mt = 0; mt < 2; ++mt)
#pragma unroll
    for (int nt = 0; nt < 2; ++nt)
#pragma unroll
      for (int r = 0; r < 4; ++r) {
        const long row = m0 + wrow * 32 + mt * 16 + quad * 4 + r;
        const long col = n0 + wcol * 32 + nt * 16 + l16;
        const float v = acc[mt][nt][r] * scale;
        const long off = (long)z * sC +
                         (split_heads ? ((col >> 6) * ((long)M * 64) + row * 64 + (col & 63))
                                      : (row * (long)N + col));
        if (mode == 2) {
          const bf16 hi = (bf16)v;
          C[off] = hi;
          C2[off] = (bf16)(v - (float)hi);
        } else {
          C[off] = (bf16)v;
        }
      }
}

// ---- plain bf16 GEMM (output projection): C = A(MxK) * Bt[n][k], out f32. ----
template <int BM, int BN>
__global__ __launch_bounds__(256) void k_gemm_bt(
    const bf16* __restrict__ A, const bf16* __restrict__ Bt, float* __restrict__ C,
    int M, int N, int K) {
  constexpr int BK = 32, LDR = BK + 8;
  constexpr int MT = BM / 32, NT = BN / 32;
  __shared__ __align__(16) bf16 As[BM * LDR];
  __shared__ __align__(16) bf16 Bs[BN * LDR];
  const int tid = threadIdx.x, wave = tid >> 6, lane = tid & 63;
  const int quad = lane >> 4, l16 = lane & 15;
  const int wrow = wave >> 1, wcol = wave & 1;
  const long m0 = (long)blockIdx.y * BM, n0 = (long)blockIdx.x * BN;
  f32x4 acc[MT][NT];
#pragma unroll
  for (int mt = 0; mt < MT; ++mt)
#pragma unroll
    for (int nt = 0; nt < NT; ++nt) acc[mt][nt] = (f32x4){0.f, 0.f, 0.f, 0.f};
  constexpr int ACH = BM * BK / 8 / 256;
  constexpr int BCH = BN * BK / 8 / 256;
  for (int k0 = 0; k0 < K; k0 += BK) {
#pragma unroll
    for (int i = 0; i < ACH; ++i) {
      const int c = i * 256 + tid, r = c >> 2, c4 = c & 3;
      *(bf16x8*)&As[r * LDR + c4 * 8] = *(const bf16x8*)&A[(m0 + r) * K + k0 + c4 * 8];
    }
#pragma unroll
    for (int i = 0; i < BCH; ++i) {
      const int c = i * 256 + tid, r = c >> 2, c4 = c & 3;
      *(bf16x8*)&Bs[r * LDR + c4 * 8] = *(const bf16x8*)&Bt[(n0 + r) * K + k0 + c4 * 8];
    }
    __syncthreads();
    bf16x8 af[MT], bfr[NT];
#pragma unroll
    for (int mt = 0; mt < MT; ++mt)
      af[mt] = *(const bf16x8*)&As[(wrow * MT * 16 + mt * 16 + l16) * LDR + quad * 8];
#pragma unroll
    for (int nt = 0; nt < NT; ++nt)
      bfr[nt] = *(const bf16x8*)&Bs[(wcol * NT * 16 + nt * 16 + l16) * LDR + quad * 8];
#pragma unroll
    for (int mt = 0; mt < MT; ++mt)
#pragma unroll
      for (int nt = 0; nt < NT; ++nt)
        acc[mt][nt] = MFMA16(af[mt], bfr[nt], acc[mt][nt]);
    __syncthreads();
  }
#pragma unroll
  for (int mt = 0; mt < MT; ++mt)
#pragma unroll
    for (int nt = 0; nt < NT; ++nt)
#pragma unroll
      for (int r = 0; r < 4; ++r) {
        const long row = m0 + wrow * MT * 16 + mt * 16 + quad * 4 + r;
        const long col = n0 + wcol * NT * 16 + nt * 16 + l16;
        C[row * (long)N + col] = acc[mt][nt][r];
      }
}

// ---- causal flash attention (unchanged from round 9) ----
__global__ __launch_bounds__(256) void k_attn(
    const bf16* __restrict__ Qhi, const bf16* __restrict__ Qlo,
    const bf16* __restrict__ Khi, const bf16* __restrict__ Klo,
    const bf16* __restrict__ Vtg, bf16* __restrict__ Og) {
  __shared__ __align__(16) bf16 KhiS[2 * 64 * 72], KloS[2 * 64 * 72];
  __shared__ __align__(16) bf16 VtS[2 * 64 * 72];
  __shared__ __align__(16) bf16 Ps[4 * 32 * 72];
  const int p = blockIdx.x, bh = blockIdx.y;
  const int b = bh >> 4, hh = bh & 15;
  const int tid = threadIdx.x, wave = tid >> 6, lane = tid & 63;
  const int quad = lane >> 4, l16 = lane & 15;
  const long bhS = (long)bh * 1024 * 64;
  const bf16* KhiG = Khi + bhS;
  const bf16* KloG = Klo + bhS;
  const bf16* VtG = Vtg + (long)bh * 64 * 1024;
  const int qbwA = p * 128 + wave * 32;
  const int qbwB = (7 - p) * 128 + wave * 32;
  bf16x8 qhA[2][2], qlA[2][2], qhB[2][2], qlB[2][2];
#pragma unroll
  for (int m = 0; m < 2; ++m) {
    const long rA = (long)(qbwA + m * 16 + l16) * 64;
    const long rB = (long)(qbwB + m * 16 + l16) * 64;
#pragma unroll
    for (int s = 0; s < 2; ++s) {
      qhA[m][s] = *(const bf16x8*)&Qhi[bhS + rA + s * 32 + quad * 8];
      qlA[m][s] = *(const bf16x8*)&Qlo[bhS + rA + s * 32 + quad * 8];
      qhB[m][s] = *(const bf16x8*)&Qhi[bhS + rB + s * 32 + quad * 8];
      qlB[m][s] = *(const bf16x8*)&Qlo[bhS + rB + s * 32 + quad * 8];
    }
  }
  bf16x8 ones8;
#pragma unroll
  for (int j = 0; j < 8; ++j) ones8[j] = (bf16)1.0f;
  const f32x4 zero4 = {0.f, 0.f, 0.f, 0.f};
  f32x4 oA[2][4], oB[2][4];
  float mA[2][4], lA[2][4], mB[2][4], lB[2][4];
#pragma unroll
  for (int m = 0; m < 2; ++m)
#pragma unroll
    for (int r = 0; r < 4; ++r) {
      mA[m][r] = -1.0e30f; lA[m][r] = 0.f;
      mB[m][r] = -1.0e30f; lB[m][r] = 0.f;
    }
#pragma unroll
  for (int m = 0; m < 2; ++m)
#pragma unroll
    for (int nt = 0; nt < 4; ++nt) { oA[m][nt] = zero4; oB[m][nt] = zero4; }

  bf16x8 sKh[2], sKl[2], sVt[2];
  auto load_regs = [&](int kc) {
    const int kb = kc * 64;
#pragma unroll
    for (int i = 0; i < 2; ++i) {
      const int c = i * 256 + tid, r = c >> 3, c8 = c & 7;
      sKh[i] = *(const bf16x8*)&KhiG[(long)(kb + r) * 64 + c8 * 8];
      sKl[i] = *(const bf16x8*)&KloG[(long)(kb + r) * 64 + c8 * 8];
      sVt[i] = *(const bf16x8*)&VtG[(long)r * 1024 + kb + c8 * 8];
    }
  };
  auto write_lds = [&](int buf) {
    const int o = buf * 64 * 72;
#pragma unroll
    for (int i = 0; i < 2; ++i) {
      const int c = i * 256 + tid, r = c >> 3, c8 = c & 7;
      *(bf16x8*)&KhiS[o + r * 72 + c8 * 8] = sKh[i];
      *(bf16x8*)&KloS[o + r * 72 + c8 * 8] = sKl[i];
      *(bf16x8*)&VtS[o + r * 72 + c8 * 8] = sVt[i];
    }
  };
  auto tile_compute = [&](const bf16x8 (&qh)[2][2], const bf16x8 (&ql)[2][2],
                          f32x4 (&o)[2][4], float (&m_i)[2][4], float (&l_i)[2][4],
                          int qbw, int kb, int buf) {
    const int ob = buf * 64 * 72;
    f32x4 sc[2][4];
#pragma unroll
    for (int ct = 0; ct < 4; ++ct) {
      const int krow = ob + (ct * 16 + l16) * 72;
      const bf16x8 kh0 = *(const bf16x8*)&KhiS[krow + quad * 8];
      const bf16x8 kh1 = *(const bf16x8*)&KhiS[krow + 32 + quad * 8];
      const bf16x8 kl0 = *(const bf16x8*)&KloS[krow + quad * 8];
      const bf16x8 kl1 = *(const bf16x8*)&KloS[krow + 32 + quad * 8];
#pragma unroll
      for (int m = 0; m < 2; ++m) {
        f32x4 s = MFMA16(qh[m][0], kh0, zero4);
        s = MFMA16(qh[m][1], kh1, s);
        s = MFMA16(qh[m][0], kl0, s);
        s = MFMA16(qh[m][1], kl1, s);
        s = MFMA16(ql[m][0], kh0, s);
        s = MFMA16(ql[m][1], kh1, s);
        sc[m][ct] = s;
      }
    }
    if (kb + 63 > qbw) {
#pragma unroll
      for (int ct = 0; ct < 4; ++ct) {
        const int col = kb + ct * 16 + l16;
#pragma unroll
        for (int m = 0; m < 2; ++m)
#pragma unroll
          for (int r = 0; r < 4; ++r) {
            const int row = qbw + m * 16 + quad * 4 + r;
            if (col > row) sc[m][ct][r] = -1.0e30f;
          }
      }
    }
    bf16x8 ap[2][2];
    float alpha[2][4];
#pragma unroll
    for (int m = 0; m < 2; ++m) {
      float rmax[4];
#pragma unroll
      for (int r = 0; r < 4; ++r)
        rmax[r] = fmaxf(fmaxf(sc[m][0][r], sc[m][1][r]), fmaxf(sc[m][2][r], sc[m][3][r]));
#pragma unroll
      for (int off = 1; off < 16; off <<= 1)
#pragma unroll
        for (int r = 0; r < 4; ++r) rmax[r] = fmaxf(rmax[r], __shfl_xor(rmax[r], off));
#pragma unroll
      for (int r = 0; r < 4; ++r) {
        const float mnew = fmaxf(m_i[m][r], rmax[r]);
        alpha[m][r] = __builtin_amdgcn_exp2f(m_i[m][r] - mnew);
        m_i[m][r] = mnew;
      }
#pragma unroll
      for (int ct = 0; ct < 4; ++ct)
#pragma unroll
        for (int r = 0; r < 4; ++r)
          Ps[wave * 2304 + (m * 16 + quad * 4 + r) * 72 + ct * 16 + l16] =
              (bf16)__builtin_amdgcn_exp2f(sc[m][ct][r] - m_i[m][r]);
      ap[m][0] = *(const bf16x8*)&Ps[wave * 2304 + (m * 16 + l16) * 72 + quad * 8];
      ap[m][1] = *(const bf16x8*)&Ps[wave * 2304 + (m * 16 + l16) * 72 + 32 + quad * 8];
      f32x4 rs = MFMA16(ap[m][0], ones8, zero4);
      rs = MFMA16(ap[m][1], ones8, rs);
#pragma unroll
      for (int r = 0; r < 4; ++r) l_i[m][r] = l_i[m][r] * alpha[m][r] + rs[r];
#pragma unroll
      for (int nt = 0; nt < 4; ++nt)
#pragma unroll
        for (int r = 0; r < 4; ++r) o[m][nt][r] *= alpha[m][r];
    }
#pragma unroll
    for (int nt = 0; nt < 4; ++nt) {
      const bf16x8 bv0 = *(const bf16x8*)&VtS[ob + (nt * 16 + l16) * 72 + quad * 8];
      const bf16x8 bv1 = *(const bf16x8*)&VtS[ob + (nt * 16 + l16) * 72 + 32 + quad * 8];
#pragma unroll
      for (int m = 0; m < 2; ++m) {
        o[m][nt] = MFMA16(ap[m][0], bv0, o[m][nt]);
        o[m][nt] = MFMA16(ap[m][1], bv1, o[m][nt]);
      }
    }
  };

  const int nch = 2 * (7 - p) + 2;
  load_regs(0);
  write_lds(0);
  __syncthreads();
  for (int kc = 0; kc < nch; ++kc) {
    const int kb = kc * 64;
    const int buf = kc & 1;
    if (kc + 1 < nch) load_regs(kc + 1);
    if (kb <= qbwA + 31) tile_compute(qhA, qlA, oA, mA, lA, qbwA, kb, buf);
    if (kb <= qbwB + 31) tile_compute(qhB, qlB, oB, mB, lB, qbwB, kb, buf);
    if (kc + 1 < nch) write_lds(1 - buf);
    __syncthreads();
  }
#pragma unroll
  for (int t = 0; t < 2; ++t) {
    const int qbw = t ? qbwB : qbwA;
#pragma unroll
    for (int m = 0; m < 2; ++m) {
      float inv[4];
#pragma unroll
      for (int r = 0; r < 4; ++r) inv[r] = 1.f / (t ? lB[m][r] : lA[m][r]);
#pragma unroll
      for (int nt = 0; nt < 4; ++nt)
#pragma unroll
        for (int r = 0; r < 4; ++r) {
          const int row = qbw + m * 16 + quad * 4 + r;
          const float v = (t ? oB[m][nt][r] : oA[m][nt][r]) * inv[r];
          Og[((long)b * 1024 + row) * 1024 + hh * 64 + nt * 16 + l16] = (bf16)v;
        }
    }
  }
}

extern "C" void kernel_launch(void* const* d_in, const int* in_sizes, int n_in,
                              void* d_out, int out_size, void* d_ws, size_t ws_size,
                              hipStream_t stream) {
  const float* x = (const float*)d_in[0];
  const float* cw = (const float*)d_in[1];
  const int* cidx = (const int*)d_in[2];
  const float* wq = (const float*)d_in[3];
  const int* iq = (const int*)d_in[4];
  const float* wk = (const float*)d_in[5];
  const int* ik = (const int*)d_in[6];
  const float* wv = (const float*)d_in[7];
  const int* iv = (const int*)d_in[8];
  const float* neurons = (const float*)d_in[9];
  const float* pool = (const float*)d_in[10];
  const float* WO = (const float*)d_in[11];
  float* out = (float*)d_out;
  char* ws = (char*)d_ws;
  // Workspace (86 MB peak, lifetime-overlapped):
  //   [ 0,16) Khi | [16,32) Klo | [32,48) Vt (all bf16)
  //   [48,64) att bf16 -- prep overlay: Wc f32 [48,52), Wn f32 [52,64)
  //   [64,66) WcTh | [66,68) WcTl   bf16 [8][128][1024]
  //   [68,74) Wth  | [74,80) Wtl    bf16 [24][1024][128]
  //   [80,82) hh   | [82,84) hl     bf16 [8][1024][128]
  //   [84,86) WOb bf16
  //   Qhi/Qlo bf16 in d_out (2 x 16 MB), dead before the final f32 write.
  bf16* Khi = (bf16*)(ws + (0l << 20));
  bf16* Klo = (bf16*)(ws + (16l << 20));
  bf16* Vt = (bf16*)(ws + (32l << 20));
  bf16* att = (bf16*)(ws + (48l << 20));
  float* Wc = (float*)(ws + (48l << 20));
  float* Wn = (float*)(ws + (52l << 20));
  bf16* WcTh = (bf16*)(ws + (64l << 20));
  bf16* WcTl = (bf16*)(ws + (66l << 20));
  bf16* Wth = (bf16*)(ws + (68l << 20));
  bf16* Wtl = (bf16*)(ws + (74l << 20));
  bf16* hh = (bf16*)(ws + (80l << 20));
  bf16* hl = (bf16*)(ws + (82l << 20));
  bf16* WOb = (bf16*)(ws + (84l << 20));
  bf16* Qhi = (bf16*)d_out;
  bf16* Qlo = (bf16*)d_out + (8l << 20);

  k_cvt<<<1024, 256, 0, stream>>>(WO, WOb, 1024l * 1024);
  k_build_wc<<<dim3(1024, 8), 128, 0, stream>>>(neurons, cw, cidx, Wc);
  k_build_mix<<<dim3(4, 128, 24), 256, 0, stream>>>(pool, wq, iq, wk, ik, wv, iv, Wn);
  k_transpose_split<<<dim3(2, 16, 8), 256, 0, stream>>>(Wc, WcTh, WcTl, 1024, 128);
  k_transpose_split<<<dim3(16, 2, 24), 256, 0, stream>>>(Wn, Wth, Wtl, 128, 1024);
  // h = x * Wc (split A in-kernel, dual B), out split-pair hh/hl [8][1024][128]
  k_gemm_h<<<dim3(2, 16, 8), 256, 0, stream>>>(
      x, WcTh, WcTl, hh, hl, 1024, 128, 1024, 1l << 20, 1l << 17, 1l << 17);
  // Q = (h*Wq) * (log2e/8), split-pair out, head-split
  k_gemm_dual<true><<<dim3(16, 16, 8), 256, 0, stream>>>(
      hh, hl, Wth, Wtl, Qhi, Qlo, 1024, 1024, 128, 1l << 17, 1l << 17, 1l << 20,
      1, 2, 0.125f * 1.44269504088896f);
  // K split-pair out, head-split
  k_gemm_dual<true><<<dim3(16, 16, 8), 256, 0, stream>>>(
      hh, hl, Wth + (8l << 17), Wtl + (8l << 17), Khi, Klo, 1024, 1024, 128,
      1l << 17, 1l << 17, 1l << 20, 1, 2, 1.f);
  // V^T: A=Wt_V (hi only), B=h (hi only), plain bf16 out [b][d][s]
  k_gemm_dual<false><<<dim3(16, 16, 8), 256, 0, stream>>>(
      Wth + (16l << 17), nullptr, hh, nullptr, Vt, nullptr, 1024, 1024, 128,
      1l << 17, 1l << 17, 1l << 20, 0, 0, 1.f);
  k_attn<<<dim3(4, 128), 256, 0, stream>>>(Qhi, Qlo, Khi, Klo, Vt, att);
  // out(f32, 8192x1024) = att * W_O^T
  k_gemm_bt<128, 128><<<dim3(8, 64, 1), 256, 0, stream>>>(att, WOb, out, 8192, 1024, 1024);
}